// Round 1
// baseline (78.663 us; speedup 1.0000x reference)
//
#include <hip/hip_runtime.h>

// SwitchReverseTriu: out[b,c,i] = rev[b] ? x[b,c,L-1-i] : x[b,c,i]
// x: (16, 32, 99681) fp32, rev: (16,) bool (passed as int32 per harness convention)

#define L_DIM 99681
#define C_DIM 32
#define B_DIM 16
#define CL (C_DIM * L_DIM)          // 3,189,792 (divisible by 4)
#define N_ELEM (B_DIM * CL)         // 51,036,672
#define N4 (N_ELEM / 4)             // 12,759,168

__global__ __launch_bounds__(256) void SwitchReverseTriu_kernel(
    const float* __restrict__ x,
    const int* __restrict__ rev,
    float* __restrict__ out)
{
    const float4* __restrict__ x4 = reinterpret_cast<const float4*>(x);
    float4* __restrict__ o4 = reinterpret_cast<float4*>(out);

    const int stride = gridDim.x * blockDim.x;
    for (int f4 = blockIdx.x * blockDim.x + threadIdx.x; f4 < N4; f4 += stride) {
        const int e0 = f4 * 4;            // flat element index of first lane-element
        const int b  = e0 / CL;           // constant-divisor -> magic multiply
        const int m  = e0 - b * CL;

        if (rev[b]) {
            int c = m / L_DIM;            // constant-divisor -> magic multiply
            int i = m - c * L_DIM;
            const float* __restrict__ xb = x + b * CL;
            float v0, v1, v2, v3;
            // 4 consecutive output elements; may cross one row boundary (L odd)
            {
                if (i == L_DIM) { i = 0; ++c; }
                v0 = xb[c * L_DIM + (L_DIM - 1 - i)]; ++i;
                if (i == L_DIM) { i = 0; ++c; }
                v1 = xb[c * L_DIM + (L_DIM - 1 - i)]; ++i;
                if (i == L_DIM) { i = 0; ++c; }
                v2 = xb[c * L_DIM + (L_DIM - 1 - i)]; ++i;
                if (i == L_DIM) { i = 0; ++c; }
                v3 = xb[c * L_DIM + (L_DIM - 1 - i)];
            }
            o4[f4] = make_float4(v0, v1, v2, v3);
        } else {
            o4[f4] = x4[f4];
        }
    }
}

extern "C" void kernel_launch(void* const* d_in, const int* in_sizes, int n_in,
                              void* d_out, int out_size, void* d_ws, size_t ws_size,
                              hipStream_t stream) {
    const float* x  = (const float*)d_in[0];
    const int* rev  = (const int*)d_in[1];
    float* out      = (float*)d_out;

    const int threads = 256;
    const int blocks  = 2048;   // grid-stride; ~24 float4 iters/thread
    SwitchReverseTriu_kernel<<<blocks, threads, 0, stream>>>(x, rev, out);
}